// Round 3
// baseline (883.048 us; speedup 1.0000x reference)
//
#include <hip/hip_runtime.h>

// Asym_Attention on MI355X (gfx950) — round 3.
// Pipeline: [convert f32->bf16] [gemm 256^2 8-phase: qkv] [flash attn] [gemm 256^2 8-phase: proj]
// ws (u16): Ah(37.75M, reused as oh) | Bh(1.77M) | Ph(0.59M) | q|k|vT (3x37.75M) = 306.7 MB

typedef unsigned short u16;
typedef unsigned int   u32;
typedef float f32x4 __attribute__((ext_vector_type(4)));
typedef short bfrag  __attribute__((ext_vector_type(8)));   // 8 bf16 (4 VGPRs)

__device__ __forceinline__ f32x4 mfma16(bfrag a, bfrag b, f32x4 c) {
  return __builtin_amdgcn_mfma_f32_16x16x32_bf16(a, b, c, 0, 0, 0);
}
__device__ __forceinline__ u16 bf16_rn(float f) {
  u32 u = __builtin_bit_cast(u32, f);
  return (u16)((u + 0x7fffu + ((u >> 16) & 1u)) >> 16);
}
__device__ __forceinline__ u32 pack_rn(float a, float b) {
  u32 ua = __builtin_bit_cast(u32, a), ub = __builtin_bit_cast(u32, b);
  ua = (ua + 0x7fffu + ((ua >> 16) & 1u)) >> 16;
  ub = (ub + 0x7fffu + ((ub >> 16) & 1u)) & 0xffff0000u;
  return ua | ub;
}
__device__ __forceinline__ void gll16(const u16* g, u16* l) {
  __builtin_amdgcn_global_load_lds((const __attribute__((address_space(1))) void*)g,
                                   (__attribute__((address_space(3))) void*)l, 16, 0, 0);
}

// ---------------- convert: f32 -> bf16 (rn) ----------------
__global__ __launch_bounds__(256)
void convert_kernel(const float* __restrict__ xv, const float* __restrict__ xi,
                    const float* __restrict__ wq, const float* __restrict__ wp,
                    u16* __restrict__ Ah, u16* __restrict__ Bh, u16* __restrict__ Ph) {
  const size_t NA = (size_t)49152 * 768, NB = (size_t)2304 * 768, NP = (size_t)768 * 768;
  const size_t HALF = (size_t)24576 * 768;
  size_t tid = (size_t)blockIdx.x * 256 + threadIdx.x;
  size_t stride = (size_t)gridDim.x * 256;
  for (size_t i = tid; i < NA / 8; i += stride) {
    size_t e = i * 8;
    const float* s = (e < HALF) ? (xv + e) : (xi + (e - HALF));
    float4 a = ((const float4*)s)[0], b = ((const float4*)s)[1];
    ((uint4*)Ah)[i] = make_uint4(pack_rn(a.x, a.y), pack_rn(a.z, a.w),
                                 pack_rn(b.x, b.y), pack_rn(b.z, b.w));
  }
  for (size_t i = tid; i < NB / 8; i += stride) {
    float4 a = ((const float4*)(wq + i * 8))[0], b = ((const float4*)(wq + i * 8))[1];
    ((uint4*)Bh)[i] = make_uint4(pack_rn(a.x, a.y), pack_rn(a.z, a.w),
                                 pack_rn(b.x, b.y), pack_rn(b.z, b.w));
  }
  for (size_t i = tid; i < NP / 8; i += stride) {
    float4 a = ((const float4*)(wp + i * 8))[0], b = ((const float4*)(wp + i * 8))[1];
    ((uint4*)Ph)[i] = make_uint4(pack_rn(a.x, a.y), pack_rn(a.z, a.w),
                                 pack_rn(b.x, b.y), pack_rn(b.z, b.w));
  }
}

// ---------------- 256^2 8-phase bf16 GEMM (C = A * B^T), K = 768 ----------------
// 512 thr = 8 waves (2M x 4N); per-wave C = 128x64 = acc[8][4]; BK=64; dbuf LDS 128 KiB.
// LDS granule swizzle: slot g at row r holds src granule g^(r&7); staged with
// pre-swizzled GLOBAL source + linear LDS dest (both-sides rule).
// Per K-tile phases: ph1 (Q00: 12 ds) | ph2 (Q01: 4 ds) | ph3 (Q10: 8 ds + stage B[t+2])
//                  | ph4 (Q11: 0 ds + stage A[t+2], vmcnt(8), barrier).
#define PHASE_BAR() do { __builtin_amdgcn_sched_barrier(0); \
                         __builtin_amdgcn_s_barrier();      \
                         __builtin_amdgcn_sched_barrier(0); } while (0)

#define STAGE_A(buf, kt, j) \
  gll16(aS + (size_t)((j) * 64) * 768 + (kt) * 64, &LA[buf][((j) * 64 + w * 8) * 64])
#define STAGE_B(buf, kt, j) \
  gll16(bS + (size_t)((j) * 64) * 768 + (kt) * 64, &LB[buf][((j) * 64 + w * 8) * 64])

#define LOAD_A(buf, s)                                                          \
  _Pragma("unroll") for (int fr = 0; fr < 4; fr++) {                            \
    int row = wm * 128 + (s) * 64 + fr * 16 + l15;                              \
    _Pragma("unroll") for (int kk = 0; kk < 2; kk++)                            \
      a_[fr][kk] = *(const bfrag*)&LA[buf][row * 64 + (((kk * 4 + lg) ^ (row & 7)) * 8)]; \
  }
#define LOAD_B(buf, ns)                                                         \
  _Pragma("unroll") for (int cf = 0; cf < 2; cf++) {                            \
    int row = wn * 64 + (ns) * 32 + cf * 16 + l15;                              \
    _Pragma("unroll") for (int kk = 0; kk < 2; kk++)                            \
      b_[ns][cf][kk] = *(const bfrag*)&LB[buf][row * 64 + (((kk * 4 + lg) ^ (row & 7)) * 8)]; \
  }
#define MFMA_Q(ms, ns)                                                          \
  do {                                                                          \
    __builtin_amdgcn_s_setprio(1);                                              \
    _Pragma("unroll") for (int fr = 0; fr < 4; fr++)                            \
      _Pragma("unroll") for (int cf = 0; cf < 2; cf++)                          \
        _Pragma("unroll") for (int kk = 0; kk < 2; kk++)                        \
          acc[(ms) * 4 + fr][(ns) * 2 + cf] =                                   \
              mfma16(a_[fr][kk], b_[ns][cf][kk], acc[(ms) * 4 + fr][(ns) * 2 + cf]); \
    __builtin_amdgcn_s_setprio(0);                                              \
  } while (0)

template <int EPI, int NBLK>
__global__ __launch_bounds__(512, 2)
void gemm_8ph(const u16* __restrict__ Ag, const u16* __restrict__ Bg,
              const float* __restrict__ bias,
              u16* __restrict__ qo, u16* __restrict__ ko, u16* __restrict__ vo,
              float* __restrict__ outp) {
  __shared__ u16 LA[2][256 * 64];
  __shared__ u16 LB[2][256 * 64];

  const int cpx = gridDim.x >> 3;
  const int bid = (blockIdx.x & 7) * cpx + (blockIdx.x >> 3);
  const int nb = bid % NBLK, mb = bid / NBLK;
  const int t = threadIdx.x;
  const int lane = t & 63;
  const int w = t >> 6;              // wave 0..7
  const int wm = w >> 2, wn = w & 3; // 2M x 4N
  const int l15 = lane & 15, lg = lane >> 4;
  const int lr = lane >> 3, gs = (lane & 7) ^ lr;  // pre-swizzled src granule

  // staging: instr j covers rows j*64 + w*8 + (lane>>3)
  const u16* aS = Ag + (size_t)(mb * 256 + w * 8 + lr) * 768 + gs * 8;
  const u16* bS = Bg + (size_t)(nb * 256 + w * 8 + lr) * 768 + gs * 8;

  f32x4 acc[8][4];
#pragma unroll
  for (int i = 0; i < 8; i++)
#pragma unroll
    for (int j = 0; j < 4; j++) acc[i][j] = (f32x4){0.f, 0.f, 0.f, 0.f};
  bfrag a_[4][2], b_[2][2][2];

  // prologue: tiles 0 -> buf0, 1 -> buf1; wait tile 0 (8 newest outstanding ok)
#pragma unroll
  for (int j = 0; j < 4; j++) { STAGE_A(0, 0, j); }
#pragma unroll
  for (int j = 0; j < 4; j++) { STAGE_B(0, 0, j); }
#pragma unroll
  for (int j = 0; j < 4; j++) { STAGE_A(1, 1, j); }
#pragma unroll
  for (int j = 0; j < 4; j++) { STAGE_B(1, 1, j); }
  asm volatile("s_waitcnt vmcnt(8)" ::: "memory");
  PHASE_BAR();

  for (int kt = 0; kt < 12; kt++) {
    const int cur = kt & 1;
    const bool pre = (kt < 10);
    // ---- ph1: quadrant (0,0)
    LOAD_A(cur, 0);
    LOAD_B(cur, 0);
    PHASE_BAR();
    MFMA_Q(0, 0);
    PHASE_BAR();
    // ---- ph2: quadrant (0,1)
    LOAD_B(cur, 1);
    PHASE_BAR();
    MFMA_Q(0, 1);
    PHASE_BAR();
    // ---- ph3: quadrant (1,0); B reads of tile kt done -> stage B[kt+2]
    LOAD_A(cur, 1);
    if (pre) {
#pragma unroll
      for (int j = 0; j < 4; j++) { STAGE_B(cur, kt + 2, j); }
    }
    PHASE_BAR();
    MFMA_Q(1, 0);
    PHASE_BAR();
    // ---- ph4: quadrant (1,1); A reads done -> stage A[kt+2]; counted vmcnt
    if (pre) {
#pragma unroll
      for (int j = 0; j < 4; j++) { STAGE_A(cur, kt + 2, j); }
    }
    PHASE_BAR();
    MFMA_Q(1, 1);
    __builtin_amdgcn_sched_barrier(0);
    if (kt < 11) {
      if (pre) asm volatile("s_waitcnt vmcnt(8)" ::: "memory");
      else     asm volatile("s_waitcnt vmcnt(0)" ::: "memory");
    }
    __builtin_amdgcn_s_barrier();
    __builtin_amdgcn_sched_barrier(0);
  }

  // epilogue
#pragma unroll
  for (int mr = 0; mr < 8; mr++) {
#pragma unroll
    for (int nr = 0; nr < 4; nr++) {
      int n = nb * 256 + wn * 64 + nr * 16 + l15;
      float bv = bias[n];
#pragma unroll
      for (int r = 0; r < 4; r++) {
        int m = mb * 256 + wm * 128 + mr * 16 + lg * 4 + r;
        float f = acc[mr][nr][r] + bv;
        if constexpr (EPI == 0) {
          int which = n / 768;
          int hh = (n % 768) / 64;
          int d = n % 64;
          int b2i = m / 384, tok = m % 384;
          int bhn = b2i * 12 + hh;
          if (which == 0) {
            qo[((size_t)bhn * 384 + tok) * 64 + d] = bf16_rn(f * 0.125f);  // fold softmax scale
          } else if (which == 1) {
            ko[((size_t)bhn * 384 + tok) * 64 + d] = bf16_rn(f);
          } else {
            vo[((size_t)bhn * 64 + d) * 384 + tok] = bf16_rn(f);           // V transposed
          }
        } else {
          outp[(size_t)m * 768 + n] = f;
        }
      }
    }
  }
}

// ---------------- flash attention (unchanged from round 2) ----------------
__global__ __launch_bounds__(256, 2)
void attn_kernel(const u16* __restrict__ q, const u16* __restrict__ k,
                 const u16* __restrict__ vT, u16* __restrict__ oh) {
  __shared__ u16 KL[64 * 64];
  __shared__ u16 VL[64 * 64];
  __shared__ float PL[4][16 * 68];

  const int cpx = gridDim.x >> 3;
  const int bid = (blockIdx.x & 7) * cpx + (blockIdx.x >> 3);
  const int qb = bid % 6, bh = bid / 6;
  const int b2i = bh / 12, hh = bh % 12;
  const int q0 = qb * 64;
  const int t = threadIdx.x;
  const int lane = t & 63, wv = t >> 6;
  const int l15 = lane & 15, lg = lane >> 4;
  const int rs = t >> 2, gq = (t & 3) * 2;

  const u16* qp = q + ((size_t)bh * 384 + q0 + wv * 16 + l15) * 64 + lg * 8;
  bfrag qf0 = *(const bfrag*)(qp);
  bfrag qf1 = *(const bfrag*)(qp + 32);

  f32x4 o[4];
#pragma unroll
  for (int i = 0; i < 4; i++) o[i] = (f32x4){0.f, 0.f, 0.f, 0.f};
  float m_run[4], l_run[4];
#pragma unroll
  for (int r = 0; r < 4; r++) { m_run[r] = -1e30f; l_run[r] = 0.f; }

  const int nblk = (q0 < 128) ? 2 : 8;

  for (int kb = 0; kb < nblk; kb++) {
    int src_bh, row0;
    if (q0 < 128)      { src_bh = bh;                          row0 = kb * 64; }
    else if (kb < 2)   { src_bh = (b2i & 63) * 12 + hh;        row0 = kb * 64; }
    else if (kb < 4)   { src_bh = ((b2i & 63) + 64) * 12 + hh; row0 = (kb - 2) * 64; }
    else               { src_bh = bh;                          row0 = 128 + (kb - 4) * 64; }

    {
      const u16* krow = k + ((size_t)src_bh * 384 + row0 + rs) * 64 + gq * 8;
      uint4 ka = *(const uint4*)(krow);
      uint4 kbv = *(const uint4*)(krow + 8);
      *(uint4*)&KL[rs * 64 + ((gq ^ (rs & 7)) * 8)] = ka;
      *(uint4*)&KL[rs * 64 + (((gq + 1) ^ (rs & 7)) * 8)] = kbv;
      const u16* vrow = vT + ((size_t)src_bh * 64 + rs) * 384 + row0 + gq * 8;
      uint4 va = *(const uint4*)(vrow);
      uint4 vb = *(const uint4*)(vrow + 8);
      *(uint4*)&VL[rs * 64 + ((gq ^ (rs & 7)) * 8)] = va;
      *(uint4*)&VL[rs * 64 + (((gq + 1) ^ (rs & 7)) * 8)] = vb;
    }
    __syncthreads();

    f32x4 S[4];
#pragma unroll
    for (int nt = 0; nt < 4; nt++) S[nt] = (f32x4){0.f, 0.f, 0.f, 0.f};
#pragma unroll
    for (int nt = 0; nt < 4; nt++) {
      int row = nt * 16 + l15;
      bfrag k0f = *(const bfrag*)&KL[row * 64 + ((lg ^ (row & 7)) * 8)];
      bfrag k1f = *(const bfrag*)&KL[row * 64 + (((4 + lg) ^ (row & 7)) * 8)];
      S[nt] = mfma16(qf0, k0f, S[nt]);
      S[nt] = mfma16(qf1, k1f, S[nt]);
    }

    float ps[4];
#pragma unroll
    for (int r = 0; r < 4; r++) {
      float v = fmaxf(fmaxf(S[0][r], S[1][r]), fmaxf(S[2][r], S[3][r]));
      v = fmaxf(v, __shfl_xor(v, 1));
      v = fmaxf(v, __shfl_xor(v, 2));
      v = fmaxf(v, __shfl_xor(v, 4));
      v = fmaxf(v, __shfl_xor(v, 8));
      float nm = fmaxf(m_run[r], v);
      float fac = __expf(m_run[r] - nm);
      m_run[r] = nm;
      l_run[r] *= fac;
      o[0][r] *= fac; o[1][r] *= fac; o[2][r] *= fac; o[3][r] *= fac;
      ps[r] = 0.f;
    }
#pragma unroll
    for (int nt = 0; nt < 4; nt++)
#pragma unroll
      for (int r = 0; r < 4; r++) {
        float p = __expf(S[nt][r] - m_run[r]);
        ps[r] += p;
        PL[wv][(lg * 4 + r) * 68 + nt * 16 + l15] = p;
      }
#pragma unroll
    for (int r = 0; r < 4; r++) {
      float v = ps[r];
      v += __shfl_xor(v, 1); v += __shfl_xor(v, 2);
      v += __shfl_xor(v, 4); v += __shfl_xor(v, 8);
      l_run[r] += v;
    }
    asm volatile("s_waitcnt lgkmcnt(0)" ::: "memory");

    bfrag pf[2];
#pragma unroll
    for (int ks = 0; ks < 2; ks++) {
      const float* pr = &PL[wv][l15 * 68 + lg * 8 + ks * 32];
      float4 x0 = *(const float4*)(pr);
      float4 x1 = *(const float4*)(pr + 4);
      union { bfrag v; u32 w[4]; } pu;
      pu.w[0] = pack_rn(x0.x, x0.y);
      pu.w[1] = pack_rn(x0.z, x0.w);
      pu.w[2] = pack_rn(x1.x, x1.y);
      pu.w[3] = pack_rn(x1.z, x1.w);
      pf[ks] = pu.v;
    }
#pragma unroll
    for (int dt = 0; dt < 4; dt++) {
      int row = dt * 16 + l15;
      bfrag v0f = *(const bfrag*)&VL[row * 64 + ((lg ^ (row & 7)) * 8)];
      bfrag v1f = *(const bfrag*)&VL[row * 64 + (((4 + lg) ^ (row & 7)) * 8)];
      o[dt] = mfma16(pf[0], v0f, o[dt]);
      o[dt] = mfma16(pf[1], v1f, o[dt]);
    }
    __syncthreads();
  }

#pragma unroll
  for (int r = 0; r < 4; r++) l_run[r] = 1.f / l_run[r];
#pragma unroll
  for (int dt = 0; dt < 4; dt++)
#pragma unroll
    for (int r = 0; r < 4; r++) {
      float f = o[dt][r] * l_run[r];
      int tok = q0 + wv * 16 + lg * 4 + r;
      int col = hh * 64 + dt * 16 + l15;
      oh[((size_t)b2i * 384 + tok) * 768 + col] = bf16_rn(f);
    }
}

extern "C" void kernel_launch(void* const* d_in, const int* in_sizes, int n_in,
                              void* d_out, int out_size, void* d_ws, size_t ws_size,
                              hipStream_t stream) {
  const float* xv    = (const float*)d_in[0];
  const float* xi    = (const float*)d_in[1];
  const float* wqkv  = (const float*)d_in[2];
  const float* bqkv  = (const float*)d_in[3];
  const float* wproj = (const float*)d_in[4];
  const float* bproj = (const float*)d_in[5];
  float* outp = (float*)d_out;

  const size_t SZ = (size_t)1536 * 384 * 64;   // 37,748,736 u16
  const size_t NB = (size_t)2304 * 768;
  const size_t NP = (size_t)768 * 768;
  const size_t WS_NEED = (SZ + NB + NP + 3 * SZ) * sizeof(u16);  // 306,708,480 B
  if (ws_size < WS_NEED) {
    hipMemsetAsync(d_out, 0, (size_t)out_size * sizeof(float), stream);
    return;
  }
  u16* Ah = (u16*)d_ws;          // reused as oh after QKV gemm
  u16* Bh = Ah + SZ;
  u16* Ph = Bh + NB;
  u16* q_ = Ph + NP;
  u16* k_ = q_ + SZ;
  u16* v_ = k_ + SZ;
  u16* oh = Ah;

  convert_kernel<<<dim3(1024), 256, 0, stream>>>(xv, xi, wqkv, wproj, Ah, Bh, Ph);
  // QKV: M=49152 (192 tiles), N=2304 (9 tiles) -> 1728 blocks
  gemm_8ph<0, 9><<<dim3(1728), 512, 0, stream>>>(Ah, Bh, bqkv, q_, k_, v_, nullptr);
  attn_kernel<<<dim3(1536 * 6), 256, 0, stream>>>(q_, k_, v_, oh);
  // proj: M=49152 (192), N=768 (3) -> 576 blocks
  gemm_8ph<1, 3><<<dim3(576), 512, 0, stream>>>(oh, Ph, bproj, nullptr, nullptr, nullptr, outp);
}